// Round 1
// baseline (1509.075 us; speedup 1.0000x reference)
//
#include <hip/hip_runtime.h>

#define BB    32
#define NSEQ  1024
#define CDIM  768
#define NH    12
#define HD    64
#define LKEYS 128
#define NPOOL 128

// ---------------------------------------------------------------------------
// 1) pool: xp[b,i,c] = 0.5*(x[b,2i,c] + x[b,2i+1,c]), i < 128
// ---------------------------------------------------------------------------
__global__ __launch_bounds__(256) void pool_kernel(const float* __restrict__ x,
                                                   float* __restrict__ xp)
{
    int idx = blockIdx.x * 256 + threadIdx.x;        // over B*128*192 float4s
    int c4 = idx % 192;
    int t  = idx / 192;
    int i  = t % NPOOL;
    int b  = t / NPOOL;
    if (b >= BB) return;
    const float4* x4 = (const float4*)x;
    float4 a = x4[((size_t)(b * NSEQ + 2 * i))     * 192 + c4];
    float4 c = x4[((size_t)(b * NSEQ + 2 * i + 1)) * 192 + c4];
    float4 r;
    r.x = 0.5f * (a.x + c.x); r.y = 0.5f * (a.y + c.y);
    r.z = 0.5f * (a.z + c.z); r.w = 0.5f * (a.w + c.w);
    ((float4*)xp)[idx] = r;
}

// ---------------------------------------------------------------------------
// 2) tiled fp32 GEMM + bias: C[M,N] = A[M,K] @ B[K,N] + bias[N]
//    BM=BN=128, BK=16, 256 threads, 8x8 micro-tile. All dims divide tiles.
// ---------------------------------------------------------------------------
__global__ __launch_bounds__(256) void sgemm_bias_kernel(
    const float* __restrict__ A, int lda,
    const float* __restrict__ Bm, int ldb,
    const float* __restrict__ bias,
    float* __restrict__ Cm, int ldc,
    int M, int Nd, int K)
{
    __shared__ float As[16][132];   // transposed A tile: As[k][m], +4 pad
    __shared__ float Bs[16][132];   // Bs[k][n]

    int tid = threadIdx.x;
    int tx = tid & 15, ty = tid >> 4;
    int m0 = blockIdx.y * 128, n0 = blockIdx.x * 128;

    float acc[8][8];
#pragma unroll
    for (int i = 0; i < 8; i++)
#pragma unroll
        for (int j = 0; j < 8; j++) acc[i][j] = 0.f;

    for (int k0 = 0; k0 < K; k0 += 16) {
#pragma unroll
        for (int i = 0; i < 2; i++) {               // A tile 128x16
            int flat = tid + i * 256;               // 0..511
            int row = flat >> 2;                    // 0..127
            int kc4 = flat & 3;                     // 0..3
            float4 av = *(const float4*)&A[(size_t)(m0 + row) * lda + k0 + kc4 * 4];
            As[kc4 * 4 + 0][row] = av.x;
            As[kc4 * 4 + 1][row] = av.y;
            As[kc4 * 4 + 2][row] = av.z;
            As[kc4 * 4 + 3][row] = av.w;
        }
#pragma unroll
        for (int i = 0; i < 2; i++) {               // B tile 16x128
            int flat = tid + i * 256;
            int row = flat >> 5;                    // 0..15
            int c4  = flat & 31;                    // 0..31
            float4 bv = *(const float4*)&Bm[(size_t)(k0 + row) * ldb + n0 + c4 * 4];
            *(float4*)&Bs[row][c4 * 4] = bv;
        }
        __syncthreads();
#pragma unroll
        for (int kk = 0; kk < 16; kk++) {
            float a[8], b[8];
            *(float4*)&a[0] = *(const float4*)&As[kk][ty * 8];
            *(float4*)&a[4] = *(const float4*)&As[kk][ty * 8 + 4];
            *(float4*)&b[0] = *(const float4*)&Bs[kk][tx * 8];
            *(float4*)&b[4] = *(const float4*)&Bs[kk][tx * 8 + 4];
#pragma unroll
            for (int i = 0; i < 8; i++)
#pragma unroll
                for (int j = 0; j < 8; j++)
                    acc[i][j] += a[i] * b[j];
        }
        __syncthreads();
    }
#pragma unroll
    for (int i = 0; i < 8; i++) {
        int row = m0 + ty * 8 + i;
#pragma unroll
        for (int j4 = 0; j4 < 2; j4++) {
            int col = n0 + tx * 8 + j4 * 4;
            float4 o;
            o.x = acc[i][j4 * 4 + 0] + bias[col + 0];
            o.y = acc[i][j4 * 4 + 1] + bias[col + 1];
            o.z = acc[i][j4 * 4 + 2] + bias[col + 2];
            o.w = acc[i][j4 * 4 + 3] + bias[col + 3];
            *(float4*)&Cm[(size_t)row * ldc + col] = o;
        }
    }
}

// ---------------------------------------------------------------------------
// 3) compress + bank assembly:
//    out[b,h,l,d] = sum_s E[s,l] * kvp[b*128+s, which*768 + h*64 + d]  (l<64)
//    out[b,h,64+j,d] = bank[b, j, h*64+d]
// ---------------------------------------------------------------------------
__global__ __launch_bounds__(256) void compress_kernel(
    const float* __restrict__ kvp,
    const float* __restrict__ Ek, const float* __restrict__ Ev,
    const float* __restrict__ kbank, const float* __restrict__ vbank,
    float* __restrict__ kfull, float* __restrict__ vfull)
{
    __shared__ float Es[128 * 64];   // E[s][l]
    __shared__ float Sl[128 * 64];   // slab[s][d]

    int tid = threadIdx.x;
    int h = blockIdx.x, b = blockIdx.y, which = blockIdx.z;
    const float* E    = which ? Ev : Ek;
    const float* bank = which ? vbank : kbank;
    float* outp       = which ? vfull : kfull;

#pragma unroll
    for (int i = 0; i < 8; i++) {                   // stage E (32 KB)
        int flat = tid + i * 256;                   // 0..2047 float4s
        *(float4*)&Es[flat * 4] = *(const float4*)&E[flat * 4];
    }
    const float* src = kvp + (size_t)b * 128 * 1536 + which * 768 + h * HD;
#pragma unroll
    for (int i = 0; i < 8; i++) {                   // stage slab (32 KB)
        int flat = tid + i * 256;
        int s = flat >> 4, d4 = flat & 15;
        *(float4*)&Sl[s * 64 + d4 * 4] = *(const float4*)&src[(size_t)s * 1536 + d4 * 4];
    }
    float* outbase = outp + ((size_t)(b * NH + h)) * LKEYS * HD;
    const float* bankbase = bank + (size_t)b * 64 * CDIM + h * HD;
#pragma unroll
    for (int i = 0; i < 4; i++) {                   // bank copy (rows 64..127)
        int flat = tid + i * 256;                   // 0..1023
        int j = flat >> 4, d4 = flat & 15;
        *(float4*)&outbase[(size_t)(64 + j) * 64 + d4 * 4] =
            *(const float4*)&bankbase[(size_t)j * CDIM + d4 * 4];
    }
    __syncthreads();

    int tx = tid & 15, ty = tid >> 4;               // out: l=ty*4+i, d=tx*4+j
    float acc[4][4];
#pragma unroll
    for (int i = 0; i < 4; i++)
#pragma unroll
        for (int j = 0; j < 4; j++) acc[i][j] = 0.f;

#pragma unroll 4
    for (int s = 0; s < 128; s++) {
        float4 av = *(const float4*)&Es[s * 64 + ty * 4];
        float4 bv = *(const float4*)&Sl[s * 64 + tx * 4];
        float a[4] = {av.x, av.y, av.z, av.w};
        float bb[4] = {bv.x, bv.y, bv.z, bv.w};
#pragma unroll
        for (int i = 0; i < 4; i++)
#pragma unroll
            for (int j = 0; j < 4; j++)
                acc[i][j] += a[i] * bb[j];
    }
#pragma unroll
    for (int i = 0; i < 4; i++) {
        float4 o; o.x = acc[i][0]; o.y = acc[i][1]; o.z = acc[i][2]; o.w = acc[i][3];
        *(float4*)&outbase[(size_t)(ty * 4 + i) * 64 + tx * 4] = o;
    }
}

// ---------------------------------------------------------------------------
// 4) attention: per (b,h,qtile of 64): S = Q@K^T * 0.125 -> softmax -> @V
//    LDS union 64 KB -> 2 blocks/CU. K staged with d4 ^= (c>>3) swizzle.
// ---------------------------------------------------------------------------
__global__ __launch_bounds__(256) void attn_kernel(
    const float* __restrict__ qb, const float* __restrict__ kf,
    const float* __restrict__ vf, float* __restrict__ ob)
{
    __shared__ float smem[16384];                   // 64 KB
    float* Ks  = smem;                              // phase A: [128][64] swizzled
    float* Qs  = smem + 8192;                       //          [64][64]
    float* red = smem + 12288;                      //          [64][16]
    float* Ps  = smem;                              // phase B: [64][128]
    float* Vs  = smem + 8192;                       //          [128][64]

    int tid = threadIdx.x;
    int tx = tid & 15, ty = tid >> 4;
    int qt = blockIdx.x, h = blockIdx.y, b = blockIdx.z;

    const float* qbase = qb + ((size_t)(b * NSEQ + qt * 64)) * CDIM + h * HD;
    const float* kbase = kf + ((size_t)(b * NH + h)) * LKEYS * HD;
    const float* vbase = vf + ((size_t)(b * NH + h)) * LKEYS * HD;

#pragma unroll
    for (int i = 0; i < 8; i++) {                   // stage K swizzled
        int flat = tid + i * 256;
        int c = flat >> 4, d4 = flat & 15;
        float4 v = *(const float4*)&kbase[(size_t)c * HD + d4 * 4];
        int sw = d4 ^ (c >> 3);
        *(float4*)&Ks[c * 64 + sw * 4] = v;
    }
#pragma unroll
    for (int i = 0; i < 4; i++) {                   // stage Q
        int flat = tid + i * 256;
        int r = flat >> 4, d4 = flat & 15;
        float4 v = *(const float4*)&qbase[(size_t)r * CDIM + d4 * 4];
        *(float4*)&Qs[r * 64 + d4 * 4] = v;
    }
    __syncthreads();

    float acc[4][8];                                // rows ty*4+i, cols tx*8+j
#pragma unroll
    for (int i = 0; i < 4; i++)
#pragma unroll
        for (int j = 0; j < 8; j++) acc[i][j] = 0.f;

#pragma unroll 4
    for (int d4 = 0; d4 < 16; d4++) {
        float4 qv[4];
#pragma unroll
        for (int i = 0; i < 4; i++)
            qv[i] = *(const float4*)&Qs[(ty * 4 + i) * 64 + d4 * 4];
#pragma unroll
        for (int j = 0; j < 8; j++) {
            int c = tx * 8 + j;
            int sw = d4 ^ (c >> 3);
            float4 kv = *(const float4*)&Ks[c * 64 + sw * 4];
#pragma unroll
            for (int i = 0; i < 4; i++)
                acc[i][j] += qv[i].x * kv.x + qv[i].y * kv.y
                           + qv[i].z * kv.z + qv[i].w * kv.w;
        }
    }

    // softmax (scale 0.125 commutes with max since it is positive)
    float rmax[4], rsum[4];
#pragma unroll
    for (int i = 0; i < 4; i++) {
        float m = acc[i][0];
#pragma unroll
        for (int j = 1; j < 8; j++) m = fmaxf(m, acc[i][j]);
        red[(ty * 4 + i) * 16 + tx] = m;
    }
    __syncthreads();
#pragma unroll
    for (int i = 0; i < 4; i++) {
        float m = -1e30f;
#pragma unroll
        for (int t2 = 0; t2 < 16; t2++) m = fmaxf(m, red[(ty * 4 + i) * 16 + t2]);
        rmax[i] = m;
    }
    __syncthreads();
#pragma unroll
    for (int i = 0; i < 4; i++) {
        float s = 0.f;
#pragma unroll
        for (int j = 0; j < 8; j++) {
            acc[i][j] = __expf((acc[i][j] - rmax[i]) * 0.125f);
            s += acc[i][j];
        }
        red[(ty * 4 + i) * 16 + tx] = s;
    }
    __syncthreads();
#pragma unroll
    for (int i = 0; i < 4; i++) {
        float s = 0.f;
#pragma unroll
        for (int t2 = 0; t2 < 16; t2++) s += red[(ty * 4 + i) * 16 + t2];
        rsum[i] = 1.f / s;
    }
    __syncthreads();                                // red/Qs/Ks dead after this

#pragma unroll
    for (int i = 0; i < 4; i++) {                   // write normalized P
#pragma unroll
        for (int j4 = 0; j4 < 2; j4++) {
            float4 o;
            o.x = acc[i][j4 * 4 + 0] * rsum[i];
            o.y = acc[i][j4 * 4 + 1] * rsum[i];
            o.z = acc[i][j4 * 4 + 2] * rsum[i];
            o.w = acc[i][j4 * 4 + 3] * rsum[i];
            *(float4*)&Ps[(ty * 4 + i) * 128 + tx * 8 + j4 * 4] = o;
        }
    }
#pragma unroll
    for (int i = 0; i < 8; i++) {                   // stage V
        int flat = tid + i * 256;
        int n = flat >> 4, d4 = flat & 15;
        *(float4*)&Vs[n * 64 + d4 * 4] = *(const float4*)&vbase[(size_t)n * HD + d4 * 4];
    }
    __syncthreads();

    float oacc[4][4];                               // rows ty*4+i, cols tx*4+j
#pragma unroll
    for (int i = 0; i < 4; i++)
#pragma unroll
        for (int j = 0; j < 4; j++) oacc[i][j] = 0.f;

#pragma unroll 8
    for (int n4 = 0; n4 < 32; n4++) {
        float p[4][4];
#pragma unroll
        for (int i = 0; i < 4; i++)
            *(float4*)&p[i][0] = *(const float4*)&Ps[(ty * 4 + i) * 128 + n4 * 4];
#pragma unroll
        for (int k = 0; k < 4; k++) {
            float4 vv = *(const float4*)&Vs[(n4 * 4 + k) * 64 + tx * 4];
#pragma unroll
            for (int i = 0; i < 4; i++) {
                oacc[i][0] += p[i][k] * vv.x;
                oacc[i][1] += p[i][k] * vv.y;
                oacc[i][2] += p[i][k] * vv.z;
                oacc[i][3] += p[i][k] * vv.w;
            }
        }
    }
    float* obase = ob + ((size_t)(b * NSEQ + qt * 64)) * CDIM + h * HD;
#pragma unroll
    for (int i = 0; i < 4; i++) {
        float4 o; o.x = oacc[i][0]; o.y = oacc[i][1]; o.z = oacc[i][2]; o.w = oacc[i][3];
        *(float4*)&obase[(size_t)(ty * 4 + i) * CDIM + tx * 4] = o;
    }
}

// ---------------------------------------------------------------------------
// launch
// ---------------------------------------------------------------------------
extern "C" void kernel_launch(void* const* d_in, const int* in_sizes, int n_in,
                              void* d_out, int out_size, void* d_ws, size_t ws_size,
                              hipStream_t stream)
{
    const float* x     = (const float*)d_in[0];
    const float* Wqkv  = (const float*)d_in[1];
    const float* bqkv  = (const float*)d_in[2];
    const float* Ek    = (const float*)d_in[3];
    const float* Ev    = (const float*)d_in[4];
    const float* Wproj = (const float*)d_in[5];
    const float* bproj = (const float*)d_in[6];
    const float* kbank = (const float*)d_in[7];
    const float* vbank = (const float*)d_in[8];
    float* out = (float*)d_out;
    float* ws  = (float*)d_ws;

    // workspace layout (floats); xp aliases qbuf, kvp aliases attn_out
    // (time-disjoint lifetimes). total = 56,623,104 floats = 226.5 MB.
    float* xp       = ws;                           // 3,145,728   (dead after kv gemm)
    float* qbuf     = ws;                           // 25,165,824
    float* kvp      = ws + 25165824;                // 6,291,456   (dead after compress)
    float* attn_out = ws + 25165824;                // 25,165,824
    float* k_full   = ws + 50331648;                // 3,145,728
    float* v_full   = ws + 53477376;                // 3,145,728

    pool_kernel<<<3072, 256, 0, stream>>>(x, xp);
    // KV projection: (B*128)x768 @ 768x1536 (+768 col offset in Wqkv/bqkv)
    sgemm_bias_kernel<<<dim3(12, 32), 256, 0, stream>>>(
        xp, CDIM, Wqkv + CDIM, 3 * CDIM, bqkv + CDIM, kvp, 2 * CDIM,
        4096, 2 * CDIM, CDIM);
    compress_kernel<<<dim3(NH, BB, 2), 256, 0, stream>>>(
        kvp, Ek, Ev, kbank, vbank, k_full, v_full);
    // Q projection: 32768x768 @ 768x768 (cols 0..767 of Wqkv)
    sgemm_bias_kernel<<<dim3(6, 256), 256, 0, stream>>>(
        x, CDIM, Wqkv, 3 * CDIM, bqkv, qbuf, CDIM,
        BB * NSEQ, CDIM, CDIM);
    attn_kernel<<<dim3(16, NH, BB), 256, 0, stream>>>(qbuf, k_full, v_full, attn_out);
    // output projection
    sgemm_bias_kernel<<<dim3(6, 256), 256, 0, stream>>>(
        attn_out, CDIM, Wproj, CDIM, bproj, out, CDIM,
        BB * NSEQ, CDIM, CDIM);
}

// Round 2
// 678.988 us; speedup vs baseline: 2.2225x; 2.2225x over previous
//
#include <hip/hip_runtime.h>

#define BB    32
#define NSEQ  1024
#define CDIM  768
#define NH    12
#define HD    64
#define LKEYS 128
#define NPOOL 128

typedef __bf16 bf16x8 __attribute__((ext_vector_type(8)));
typedef float  f32x4  __attribute__((ext_vector_type(4)));

__device__ __forceinline__ ushort f2bf(float f) {
    union { float f; uint u; } v; v.f = f;
    uint u = v.u;
    uint r = u + 0x7FFFu + ((u >> 16) & 1u);   // RNE
    return (ushort)(r >> 16);
}
__device__ __forceinline__ uint pack2(float x, float y) {
    return (uint)f2bf(x) | ((uint)f2bf(y) << 16);
}

// ---------------------------------------------------------------------------
// 0a) fp32 -> bf16 bulk convert (8 elements / thread)
// ---------------------------------------------------------------------------
__global__ __launch_bounds__(256) void cvt_bf16_kernel(const float* __restrict__ src,
                                                       ushort* __restrict__ dst, int n8)
{
    int idx = blockIdx.x * 256 + threadIdx.x;
    if (idx >= n8) return;
    float4 a = ((const float4*)src)[idx * 2];
    float4 b = ((const float4*)src)[idx * 2 + 1];
    uint4 o;
    o.x = pack2(a.x, a.y); o.y = pack2(a.z, a.w);
    o.z = pack2(b.x, b.y); o.w = pack2(b.z, b.w);
    ((uint4*)dst)[idx] = o;
}

// ---------------------------------------------------------------------------
// 0b) transpose + convert: dst[c*R + r] = bf16(src[r*C + c])
// ---------------------------------------------------------------------------
__global__ __launch_bounds__(256) void transpose_cvt_kernel(const float* __restrict__ src,
                                                            ushort* __restrict__ dst,
                                                            int R, int C)
{
    __shared__ ushort tile[32][33];
    int bc = blockIdx.x * 32, br = blockIdx.y * 32;
    int tx = threadIdx.x & 31, ty = threadIdx.x >> 5;    // 32 x 8
#pragma unroll
    for (int i = 0; i < 32; i += 8)
        tile[ty + i][tx] = f2bf(src[(size_t)(br + ty + i) * C + bc + tx]);
    __syncthreads();
#pragma unroll
    for (int i = 0; i < 32; i += 8)
        dst[(size_t)(bc + ty + i) * R + br + tx] = tile[tx][ty + i];
}

// ---------------------------------------------------------------------------
// 1) pool: xp[b,i,c] = 0.5*(x[b,2i,c]+x[b,2i+1,c]) -> bf16, i < 128
//    8 channels / thread.
// ---------------------------------------------------------------------------
__global__ __launch_bounds__(256) void pool_kernel(const float* __restrict__ x,
                                                   ushort* __restrict__ xp)
{
    int idx = blockIdx.x * 256 + threadIdx.x;        // over B*128*96
    int c8 = idx % 96;
    int t  = idx / 96;
    int i  = t % NPOOL;
    int b  = t / NPOOL;
    if (b >= BB) return;
    const float4* x4 = (const float4*)x;
    size_t base0 = ((size_t)(b * NSEQ + 2 * i)) * 192 + c8 * 2;
    size_t base1 = base0 + 192;
    float4 a0 = x4[base0], a1 = x4[base0 + 1];
    float4 b0 = x4[base1], b1 = x4[base1 + 1];
    uint4 o;
    o.x = pack2(0.5f * (a0.x + b0.x), 0.5f * (a0.y + b0.y));
    o.y = pack2(0.5f * (a0.z + b0.z), 0.5f * (a0.w + b0.w));
    o.z = pack2(0.5f * (a1.x + b1.x), 0.5f * (a1.y + b1.y));
    o.w = pack2(0.5f * (a1.z + b1.z), 0.5f * (a1.w + b1.w));
    ((uint4*)xp)[idx] = o;
}

// ---------------------------------------------------------------------------
// 2) bf16 MFMA GEMM + bias (m97 structure): C[M,N] = A @ Bt^T + bias
//    A: MxK bf16 row-major. Bt: NxK bf16 row-major (pre-transposed B).
//    128x128 tile, BK=32, 256 thr = 4 waves in 2x2, each wave 4x4 MFMA tiles.
//    global_load_lds(16B) staging; LDS layout row-major [128][32] (lane-order
//    contiguous as required by wave-uniform-base + lane*16 semantics).
// ---------------------------------------------------------------------------
__global__ __launch_bounds__(256) void mfma_gemm_kernel(
    const ushort* __restrict__ A, const ushort* __restrict__ Bt,
    const float* __restrict__ bias, float* __restrict__ C,
    int M, int N, int K)
{
    __shared__ ushort As[128 * 32];
    __shared__ ushort Bs[128 * 32];

    int tid  = threadIdx.x;
    int wave = tid >> 6, lane = tid & 63;
    int m0 = blockIdx.y * 128, n0 = blockIdx.x * 128;
    int wm = wave >> 1, wn = wave & 1;
    int lm = lane & 15, lh = lane >> 4;

    f32x4 acc[4][4] = {};

    for (int k0 = 0; k0 < K; k0 += 32) {
        __syncthreads();
#pragma unroll
        for (int t = 0; t < 2; t++) {
            int flat = wave * 128 + t * 64 + lane;       // 16B-load index
            int row = flat >> 2, kc = (flat & 3) * 8;
            const ushort* gA = A  + (size_t)(m0 + row) * K + k0 + kc;
            const ushort* gB = Bt + (size_t)(n0 + row) * K + k0 + kc;
            __builtin_amdgcn_global_load_lds(
                (const __attribute__((address_space(1))) void*)gA,
                (__attribute__((address_space(3))) void*)(As + (size_t)(wave * 128 + t * 64) * 8),
                16, 0, 0);
            __builtin_amdgcn_global_load_lds(
                (const __attribute__((address_space(1))) void*)gB,
                (__attribute__((address_space(3))) void*)(Bs + (size_t)(wave * 128 + t * 64) * 8),
                16, 0, 0);
        }
        __syncthreads();

        bf16x8 af[4], bfr[4];
#pragma unroll
        for (int i = 0; i < 4; i++)
            af[i] = *(const bf16x8*)((const void*)&As[(wm * 64 + i * 16 + lm) * 32 + lh * 8]);
#pragma unroll
        for (int j = 0; j < 4; j++)
            bfr[j] = *(const bf16x8*)((const void*)&Bs[(wn * 64 + j * 16 + lm) * 32 + lh * 8]);
#pragma unroll
        for (int i = 0; i < 4; i++)
#pragma unroll
            for (int j = 0; j < 4; j++)
                acc[i][j] = __builtin_amdgcn_mfma_f32_16x16x32_bf16(af[i], bfr[j], acc[i][j], 0, 0, 0);
    }

    int crow = m0 + wm * 64, ccol = n0 + wn * 64;
#pragma unroll
    for (int j = 0; j < 4; j++) {
        int col = ccol + j * 16 + lm;
        float bb = bias[col];
#pragma unroll
        for (int i = 0; i < 4; i++)
#pragma unroll
            for (int r = 0; r < 4; r++)
                C[(size_t)(crow + i * 16 + lh * 4 + r) * N + col] = acc[i][j][r] + bb;
    }
}

// ---------------------------------------------------------------------------
// 3) compress + bank assembly (fp32, unchanged from R1)
// ---------------------------------------------------------------------------
__global__ __launch_bounds__(256) void compress_kernel(
    const float* __restrict__ kvp,
    const float* __restrict__ Ek, const float* __restrict__ Ev,
    const float* __restrict__ kbank, const float* __restrict__ vbank,
    float* __restrict__ kfull, float* __restrict__ vfull)
{
    __shared__ float Es[128 * 64];
    __shared__ float Sl[128 * 64];

    int tid = threadIdx.x;
    int h = blockIdx.x, b = blockIdx.y, which = blockIdx.z;
    const float* E    = which ? Ev : Ek;
    const float* bank = which ? vbank : kbank;
    float* outp       = which ? vfull : kfull;

#pragma unroll
    for (int i = 0; i < 8; i++) {
        int flat = tid + i * 256;
        *(float4*)&Es[flat * 4] = *(const float4*)&E[flat * 4];
    }
    const float* src = kvp + (size_t)b * 128 * 1536 + which * 768 + h * HD;
#pragma unroll
    for (int i = 0; i < 8; i++) {
        int flat = tid + i * 256;
        int s = flat >> 4, d4 = flat & 15;
        *(float4*)&Sl[s * 64 + d4 * 4] = *(const float4*)&src[(size_t)s * 1536 + d4 * 4];
    }
    float* outbase = outp + ((size_t)(b * NH + h)) * LKEYS * HD;
    const float* bankbase = bank + (size_t)b * 64 * CDIM + h * HD;
#pragma unroll
    for (int i = 0; i < 4; i++) {
        int flat = tid + i * 256;
        int j = flat >> 4, d4 = flat & 15;
        *(float4*)&outbase[(size_t)(64 + j) * 64 + d4 * 4] =
            *(const float4*)&bankbase[(size_t)j * CDIM + d4 * 4];
    }
    __syncthreads();

    int tx = tid & 15, ty = tid >> 4;
    float acc[4][4];
#pragma unroll
    for (int i = 0; i < 4; i++)
#pragma unroll
        for (int j = 0; j < 4; j++) acc[i][j] = 0.f;

#pragma unroll 4
    for (int s = 0; s < 128; s++) {
        float4 av = *(const float4*)&Es[s * 64 + ty * 4];
        float4 bv = *(const float4*)&Sl[s * 64 + tx * 4];
        float a[4] = {av.x, av.y, av.z, av.w};
        float bb[4] = {bv.x, bv.y, bv.z, bv.w};
#pragma unroll
        for (int i = 0; i < 4; i++)
#pragma unroll
            for (int j = 0; j < 4; j++)
                acc[i][j] += a[i] * bb[j];
    }
#pragma unroll
    for (int i = 0; i < 4; i++) {
        float4 o; o.x = acc[i][0]; o.y = acc[i][1]; o.z = acc[i][2]; o.w = acc[i][3];
        *(float4*)&outbase[(size_t)(ty * 4 + i) * 64 + tx * 4] = o;
    }
}

// ---------------------------------------------------------------------------
// 4) attention (fp32 compute, unchanged) — now writes bf16 attn_out
// ---------------------------------------------------------------------------
__global__ __launch_bounds__(256) void attn_kernel(
    const float* __restrict__ qb, const float* __restrict__ kf,
    const float* __restrict__ vf, ushort* __restrict__ ob)
{
    __shared__ float smem[16384];
    float* Ks  = smem;
    float* Qs  = smem + 8192;
    float* red = smem + 12288;
    float* Ps  = smem;
    float* Vs  = smem + 8192;

    int tid = threadIdx.x;
    int tx = tid & 15, ty = tid >> 4;
    int qt = blockIdx.x, h = blockIdx.y, b = blockIdx.z;

    const float* qbase = qb + ((size_t)(b * NSEQ + qt * 64)) * CDIM + h * HD;
    const float* kbase = kf + ((size_t)(b * NH + h)) * LKEYS * HD;
    const float* vbase = vf + ((size_t)(b * NH + h)) * LKEYS * HD;

#pragma unroll
    for (int i = 0; i < 8; i++) {
        int flat = tid + i * 256;
        int c = flat >> 4, d4 = flat & 15;
        float4 v = *(const float4*)&kbase[(size_t)c * HD + d4 * 4];
        int sw = d4 ^ (c >> 3);
        *(float4*)&Ks[c * 64 + sw * 4] = v;
    }
#pragma unroll
    for (int i = 0; i < 4; i++) {
        int flat = tid + i * 256;
        int r = flat >> 4, d4 = flat & 15;
        float4 v = *(const float4*)&qbase[(size_t)r * CDIM + d4 * 4];
        *(float4*)&Qs[r * 64 + d4 * 4] = v;
    }
    __syncthreads();

    float acc[4][8];
#pragma unroll
    for (int i = 0; i < 4; i++)
#pragma unroll
        for (int j = 0; j < 8; j++) acc[i][j] = 0.f;

#pragma unroll 4
    for (int d4 = 0; d4 < 16; d4++) {
        float4 qv[4];
#pragma unroll
        for (int i = 0; i < 4; i++)
            qv[i] = *(const float4*)&Qs[(ty * 4 + i) * 64 + d4 * 4];
#pragma unroll
        for (int j = 0; j < 8; j++) {
            int c = tx * 8 + j;
            int sw = d4 ^ (c >> 3);
            float4 kv = *(const float4*)&Ks[c * 64 + sw * 4];
#pragma unroll
            for (int i = 0; i < 4; i++)
                acc[i][j] += qv[i].x * kv.x + qv[i].y * kv.y
                           + qv[i].z * kv.z + qv[i].w * kv.w;
        }
    }

    float rmax[4], rsum[4];
#pragma unroll
    for (int i = 0; i < 4; i++) {
        float m = acc[i][0];
#pragma unroll
        for (int j = 1; j < 8; j++) m = fmaxf(m, acc[i][j]);
        red[(ty * 4 + i) * 16 + tx] = m;
    }
    __syncthreads();
#pragma unroll
    for (int i = 0; i < 4; i++) {
        float m = -1e30f;
#pragma unroll
        for (int t2 = 0; t2 < 16; t2++) m = fmaxf(m, red[(ty * 4 + i) * 16 + t2]);
        rmax[i] = m;
    }
    __syncthreads();
#pragma unroll
    for (int i = 0; i < 4; i++) {
        float s = 0.f;
#pragma unroll
        for (int j = 0; j < 8; j++) {
            acc[i][j] = __expf((acc[i][j] - rmax[i]) * 0.125f);
            s += acc[i][j];
        }
        red[(ty * 4 + i) * 16 + tx] = s;
    }
    __syncthreads();
#pragma unroll
    for (int i = 0; i < 4; i++) {
        float s = 0.f;
#pragma unroll
        for (int t2 = 0; t2 < 16; t2++) s += red[(ty * 4 + i) * 16 + t2];
        rsum[i] = 1.f / s;
    }
    __syncthreads();

#pragma unroll
    for (int i = 0; i < 4; i++) {
#pragma unroll
        for (int j4 = 0; j4 < 2; j4++) {
            float4 o;
            o.x = acc[i][j4 * 4 + 0] * rsum[i];
            o.y = acc[i][j4 * 4 + 1] * rsum[i];
            o.z = acc[i][j4 * 4 + 2] * rsum[i];
            o.w = acc[i][j4 * 4 + 3] * rsum[i];
            *(float4*)&Ps[(ty * 4 + i) * 128 + tx * 8 + j4 * 4] = o;
        }
    }
#pragma unroll
    for (int i = 0; i < 8; i++) {
        int flat = tid + i * 256;
        int n = flat >> 4, d4 = flat & 15;
        *(float4*)&Vs[n * 64 + d4 * 4] = *(const float4*)&vbase[(size_t)n * HD + d4 * 4];
    }
    __syncthreads();

    float oacc[4][4];
#pragma unroll
    for (int i = 0; i < 4; i++)
#pragma unroll
        for (int j = 0; j < 4; j++) oacc[i][j] = 0.f;

#pragma unroll 8
    for (int n4 = 0; n4 < 32; n4++) {
        float p[4][4];
#pragma unroll
        for (int i = 0; i < 4; i++)
            *(float4*)&p[i][0] = *(const float4*)&Ps[(ty * 4 + i) * 128 + n4 * 4];
#pragma unroll
        for (int k = 0; k < 4; k++) {
            float4 vv = *(const float4*)&Vs[(n4 * 4 + k) * 64 + tx * 4];
#pragma unroll
            for (int i = 0; i < 4; i++) {
                oacc[i][0] += p[i][k] * vv.x;
                oacc[i][1] += p[i][k] * vv.y;
                oacc[i][2] += p[i][k] * vv.z;
                oacc[i][3] += p[i][k] * vv.w;
            }
        }
    }
    ushort* obase = ob + ((size_t)(b * NSEQ + qt * 64)) * CDIM + h * HD;
#pragma unroll
    for (int i = 0; i < 4; i++) {
        ushort4 o;
        o.x = f2bf(oacc[i][0]); o.y = f2bf(oacc[i][1]);
        o.z = f2bf(oacc[i][2]); o.w = f2bf(oacc[i][3]);
        *(ushort4*)&obase[(size_t)(ty * 4 + i) * CDIM + tx * 4] = o;
    }
}

// ---------------------------------------------------------------------------
// launch
// ---------------------------------------------------------------------------
extern "C" void kernel_launch(void* const* d_in, const int* in_sizes, int n_in,
                              void* d_out, int out_size, void* d_ws, size_t ws_size,
                              hipStream_t stream)
{
    const float* x     = (const float*)d_in[0];
    const float* Wqkv  = (const float*)d_in[1];
    const float* bqkv  = (const float*)d_in[2];
    const float* Ek    = (const float*)d_in[3];
    const float* Ev    = (const float*)d_in[4];
    const float* Wproj = (const float*)d_in[5];
    const float* bproj = (const float*)d_in[6];
    const float* kbank = (const float*)d_in[7];
    const float* vbank = (const float*)d_in[8];
    float* out = (float*)d_out;
    float* ws  = (float*)d_ws;

    // workspace (floats) — 46,792,704 floats = 187.2 MB
    // aliases (time-disjoint): kvp shares qbuf region; attn_out shares x_bf.
    float*  qbuf   = ws;                              // 25,165,824 f
    float*  kvp    = ws;                              //  6,291,456 f (dead before qbuf write)
    ushort* x_bf   = (ushort*)(ws + 25165824);        // 25,165,824 us
    ushort* aob    = (ushort*)(ws + 25165824);        // attn_out alias (x_bf dead)
    ushort* xp_bf  = (ushort*)(ws + 37748736);        //  3,145,728 us
    ushort* Wq_t   = (ushort*)(ws + 39321600);        //  1,769,472 us (2304 x 768)
    ushort* Wp_t   = (ushort*)(ws + 40206336);        //    589,824 us (768 x 768)
    float*  k_full = ws + 40501248;                   //  3,145,728 f
    float*  v_full = ws + 43646976;                   //  3,145,728 f

    cvt_bf16_kernel<<<12288, 256, 0, stream>>>(x, x_bf, 3145728);
    transpose_cvt_kernel<<<dim3(72, 24), 256, 0, stream>>>(Wqkv, Wq_t, CDIM, 3 * CDIM);
    transpose_cvt_kernel<<<dim3(24, 24), 256, 0, stream>>>(Wproj, Wp_t, CDIM, CDIM);
    pool_kernel<<<1536, 256, 0, stream>>>(x, xp_bf);

    // KV projection: 4096 x 1536, A=xp (4096x768), Bt = Wq_t rows 768..2303
    mfma_gemm_kernel<<<dim3(12, 32), 256, 0, stream>>>(
        xp_bf, Wq_t + (size_t)CDIM * CDIM, bqkv + CDIM, kvp, 4096, 2 * CDIM, CDIM);
    compress_kernel<<<dim3(NH, BB, 2), 256, 0, stream>>>(
        kvp, Ek, Ev, kbank, vbank, k_full, v_full);

    // Q projection: 32768 x 768, Bt = Wq_t rows 0..767
    mfma_gemm_kernel<<<dim3(6, 256), 256, 0, stream>>>(
        x_bf, Wq_t, bqkv, qbuf, BB * NSEQ, CDIM, CDIM);

    attn_kernel<<<dim3(16, NH, BB), 256, 0, stream>>>(qbuf, k_full, v_full, aob);

    // output projection
    mfma_gemm_kernel<<<dim3(6, 256), 256, 0, stream>>>(
        aob, Wp_t, bproj, out, BB * NSEQ, CDIM, CDIM);
}